// Round 14
// baseline (203.117 us; speedup 1.0000x reference)
//
#include <hip/hip_runtime.h>
#include <hip/hip_bf16.h>
#include <stdint.h>
#include <math.h>

#define NB 4
#define NS 2048
#define NHID 1024
#define NHEAD 16
#define ND 64
#define NM (NB * NS)  // 8192 rows

typedef unsigned short u16;
typedef __attribute__((ext_vector_type(8))) short bf16x8;
typedef __attribute__((ext_vector_type(4))) float f32x4;

#define SC2F 0.18033688011112042f  // 0.125 * log2(e): Q pre-scale -> softmax in exp2 domain

// ---------- helpers ----------

__device__ __forceinline__ u16 f2bf(float f) {
  union { float f; unsigned u; } v; v.f = f;
  unsigned u = v.u;
  return (u16)((u + 0x7FFFu + ((u >> 16) & 1u)) >> 16);  // RNE, no NaN in data
}

// async global->LDS, 16B per lane. LDS dest is wave-uniform base; HW adds lane*16.
__device__ __forceinline__ void gload_lds16(const u16* g, u16* l) {
  __builtin_amdgcn_global_load_lds(
      (const __attribute__((address_space(1))) void*)g,
      (__attribute__((address_space(3))) void*)l, 16, 0, 0);
}

__device__ __forceinline__ f32x4 mfma16(bf16x8 a, bf16x8 b, f32x4 c) {
  return __builtin_amdgcn_mfma_f32_16x16x32_bf16(a, b, c, 0, 0, 0);
}

__device__ __forceinline__ unsigned cvtpk(float lo, float hi) {
  unsigned d;
  asm("v_cvt_pk_bf16_f32 %0, %1, %2" : "=v"(d) : "v"(lo), "v"(hi));
  return d;
}

// ---------- fp32 -> bf16 conversion (x + 4 weights in one launch) ----------

__global__ __launch_bounds__(256) void convert_f32_bf16(
    const float* __restrict__ x, const float* __restrict__ wq,
    const float* __restrict__ wk, const float* __restrict__ wv,
    const float* __restrict__ wo,
    u16* __restrict__ xb, u16* __restrict__ wqb, u16* __restrict__ wkb,
    u16* __restrict__ wvb, u16* __restrict__ wob) {
  const float* src; u16* dst; int n;
  switch (blockIdx.y) {
    case 0:  src = x;  dst = xb;  n = NM * NHID;   break;
    case 1:  src = wq; dst = wqb; n = NHID * NHID; break;
    case 2:  src = wk; dst = wkb; n = NHID * NHID; break;
    case 3:  src = wv; dst = wvb; n = NHID * NHID; break;
    default: src = wo; dst = wob; n = NHID * NHID; break;
  }
  int stride = gridDim.x * blockDim.x * 4;
  for (int i = (blockIdx.x * blockDim.x + threadIdx.x) * 4; i < n; i += stride) {
    float4 v = *reinterpret_cast<const float4*>(src + i);
    ushort4 o;
    o.x = f2bf(v.x); o.y = f2bf(v.y); o.z = f2bf(v.z); o.w = f2bf(v.w);
    *reinterpret_cast<ushort4*>(dst + i) = o;
  }
}

// ---------- 256x128 GEMM mainloop: C[m][n] = sum_k A[m][k] * Bw[n][k] ----------
// BK=32, 512 threads (8 waves as 4M x 2N, per-wave 64x64 out, acc[4][4]).
// Triple-buffered LDS (3 x 24KB = 72KB -> 2 blocks/CU), prefetch depth 2 with
// counted vmcnt(3) (never 0 in steady state). Linear LDS (BK=32 rows are
// bank-uniform for this ds_read_b128 pattern).

#define GNKT 32  // K = 1024 / BK = 32

__device__ __forceinline__ void gemm256_mainloop(
    const u16* __restrict__ A, const u16* __restrict__ Bw,
    int bm, int bn, u16 (*lds)[12288], f32x4 (&acc)[4][4]) {
  const int t = threadIdx.x;          // 0..511
  const int w = t >> 6, l = t & 63;
  const int lr = l & 15, kh = l >> 4;
  const int wm = w >> 1, wn = w & 1;  // wave grid 4M x 2N

#pragma unroll
  for (int mi = 0; mi < 4; ++mi)
#pragma unroll
    for (int ni = 0; ni < 4; ++ni) acc[mi][ni] = (f32x4){0.f, 0.f, 0.f, 0.f};

  // stage K-tile kt into lds[buf]: A[256][32] = 2 loads/lane, B[128][32] = 1
  auto stage = [&](int kt, int buf) {
    const int k0 = kt * 32;
#pragma unroll
    for (int it = 0; it < 2; ++it) {
      int idx = it * 512 + t;                       // 0..1023 16B-chunks
      int row = idx >> 2, c = idx & 3;
      gload_lds16(A + (size_t)(bm + row) * NHID + k0 + c * 8,
                  lds[buf] + (size_t)(it * 512 + w * 64) * 8);
    }
    {
      int row = t >> 2, c = t & 3;                  // 512 chunks
      gload_lds16(Bw + (size_t)(bn + row) * NHID + k0 + c * 8,
                  lds[buf] + 8192 + (size_t)(w * 64) * 8);
    }
  };

  stage(0, 0);
  stage(1, 1);

  for (int kt = 0; kt < GNKT; ++kt) {
    const int buf = kt % 3;
    // force tile kt's 3 loads complete; leave tile kt+1's 3 in flight
    if (kt < GNKT - 1) asm volatile("s_waitcnt vmcnt(3)" ::: "memory");
    else               asm volatile("s_waitcnt vmcnt(0)" ::: "memory");
    __builtin_amdgcn_s_barrier();
    if (kt + 2 < GNKT) stage(kt + 2, (kt + 2) % 3);  // buf (kt-1)%3: free since last barrier

    const u16* Ab = lds[buf];
    const u16* Bb = lds[buf] + 8192;
    bf16x8 af[4], bfr[4];
#pragma unroll
    for (int mi = 0; mi < 4; ++mi)
      af[mi] = *(const bf16x8*)&Ab[(wm * 64 + mi * 16 + lr) * 32 + kh * 8];
#pragma unroll
    for (int ni = 0; ni < 4; ++ni)
      bfr[ni] = *(const bf16x8*)&Bb[(wn * 64 + ni * 16 + lr) * 32 + kh * 8];
    __builtin_amdgcn_s_setprio(1);
#pragma unroll
    for (int mi = 0; mi < 4; ++mi)
#pragma unroll
      for (int ni = 0; ni < 4; ++ni)
        acc[mi][ni] = mfma16(af[mi], bfr[ni], acc[mi][ni]);
    __builtin_amdgcn_s_setprio(0);
  }
}

// ---------- QKV projection ----------
// Q pre-scaled by SC2F (softmax runs in exp2 domain). V written transposed [b,h,d,s]
// AND k-permuted within each 32-block so attention's PV B-operand matches the
// lane-local P fragment order (k = 16u+4g+v stored at slot 8g+4u+v).
// 1-D grid of 768 with bijective XCD swizzle (768 = 8*96): each XCD gets 96
// consecutive logical tiles sharing weight panels -> per-XCD L2 locality (T1).

__global__ __launch_bounds__(512, 4) void gemm_qkv(
    const u16* __restrict__ xb,
    const u16* __restrict__ wqb, const u16* __restrict__ wkb, const u16* __restrict__ wvb,
    const float* __restrict__ bq, const float* __restrict__ bk, const float* __restrict__ bv,
    u16* __restrict__ Qo, u16* __restrict__ Ko, u16* __restrict__ Vo) {
  __shared__ __align__(16) u16 lds[3][12288];  // 72KB: 3 x (A 256x32 + B 128x32)
  const int phys = blockIdx.x;
  const int lin = (phys & 7) * 96 + (phys >> 3);  // bijective XCD remap
  const int which = lin >> 8;          // 0..2
  const int rem = lin & 255;
  const int bm = (rem & 31) * 256;     // bm fastest: consecutive lin share weight panel
  const int bn = (rem >> 5) * 128;
  const u16* Bw = (which == 0) ? wqb : (which == 1) ? wkb : wvb;
  const float* bias = (which == 0) ? bq : (which == 1) ? bk : bv;
  u16* outp = (which == 0) ? Qo : (which == 1) ? Ko : Vo;

  f32x4 acc[4][4];
  gemm256_mainloop(xb, Bw, bm, bn, lds, acc);

  const int t = threadIdx.x, w = t >> 6, l = t & 63, lr = l & 15, kh = l >> 4;
  const int wm = w >> 1, wn = w & 1;
#pragma unroll
  for (int mi = 0; mi < 4; ++mi)
#pragma unroll
    for (int ni = 0; ni < 4; ++ni)
#pragma unroll
      for (int r = 0; r < 4; ++r) {
        int m = bm + wm * 64 + mi * 16 + kh * 4 + r;
        int n = bn + wn * 64 + ni * 16 + lr;
        float v = acc[mi][ni][r] + bias[n];
        if (which == 0) v *= SC2F;
        int b = m >> 11, s = m & (NS - 1), h = n >> 6, d = n & (ND - 1);
        size_t addr;
        if (which < 2) {
          addr = (((size_t)(b * NHEAD + h)) * NS + s) * ND + d;  // [b,h,s,d]
        } else {
          // V^T [b,h,d,s'], s' = within-32-block permute: k=16u+4g2+v -> 8g2+4u+v
          int sp = (s & ~31) | (((s >> 2) & 3) * 8 + ((s >> 4) & 1) * 4 + (s & 3));
          addr = (((size_t)(b * NHEAD + h)) * ND + d) * NS + sp;
        }
        outp[addr] = f2bf(v);
      }
}

// ---------- flash attention ----------
// R14: R12-proven sync skeleton (2 buffers, one __syncthreads per tile, stage
// right after) -- UNCHANGED. New: intra-tile mi-skew, pure source-order
// pipelining inside the region: unrolled p-loop issues QK(p) and softmax(p-2)
// interleaved, so exp2/cvt_pk VALU slots into the matrix-pipe gaps while later
// QK MFMAs queue. K fragments hoisted to kfr (dies before PV; budget 256 VGPR
// at the grid-forced 2 blocks/CU). Identical math + barriers to R12.
// R13's cross-tile 3-buffer skew FAILED correctness (unexplained; like R6) --
// do not reintroduce. R9 lesson: V fragments NOT hoisted ahead of softmax.

__global__ __launch_bounds__(256, 2) void attn_kernel(
    const u16* __restrict__ Q, const u16* __restrict__ K,
    const u16* __restrict__ Vt, u16* __restrict__ AO) {
  __shared__ __align__(16) u16 Ks[2][64 * 64];    // 16KB double-buffered
  __shared__ __align__(16) u16 Vs[2][64 * 64];    // 16KB double-buffered

  const int t = threadIdx.x, w = t >> 6, l = t & 63;
  const int lr = l & 15, g = l >> 4;
  const int bh = blockIdx.y;
  const int q0 = blockIdx.x * 256;

  const u16* Qh = Q  + (size_t)bh * NS * ND;
  const u16* Kh = K  + (size_t)bh * NS * ND;
  const u16* Vh = Vt + (size_t)bh * NS * ND;  // [d][s'] (k-permuted)

  // Q fragments straight from global into registers (no LDS round-trip)
  bf16x8 qf[4][2];
#pragma unroll
  for (int mi = 0; mi < 4; ++mi)
#pragma unroll
    for (int ks = 0; ks < 2; ++ks)
      qf[mi][ks] = *(const bf16x8*)(Qh + (size_t)(q0 + w * 64 + mi * 16 + lr) * ND + ks * 32 + g * 8);

  // all-ones bf16 B-operand (layout-proof: every element equal)
  bf16x8 ones;
#pragma unroll
  for (int i = 0; i < 8; ++i) ones[i] = (short)0x3F80;

  // stage tile kt into buffer b: 4 loads/lane, pre-swizzled source
  auto stage_kv = [&](int kt, int b) {
#pragma unroll
    for (int j = 0; j < 2; ++j) {
      int idx = j * 256 + t;
      int row = idx >> 3, sch = (idx & 7) ^ (row & 7);
      gload_lds16(Kh + (size_t)(kt + row) * ND + sch * 8, Ks[b] + (size_t)(j * 256 + w * 64) * 8);
      gload_lds16(Vh + (size_t)row * NS + kt + sch * 8,   Vs[b] + (size_t)(j * 256 + w * 64) * 8);
    }
  };

  stage_kv(0, 0);

  f32x4 o[4][4];
  f32x4 acc_l[4];  // row-sum accumulators; acc_l[mi][r] = l for row q=4g+r (matches o)
#pragma unroll
  for (int mi = 0; mi < 4; ++mi) {
#pragma unroll
    for (int ni = 0; ni < 4; ++ni) o[mi][ni] = (f32x4){0.f, 0.f, 0.f, 0.f};
    acc_l[mi] = (f32x4){0.f, 0.f, 0.f, 0.f};
  }

  const int nt = NS / 64;
  for (int ti = 0; ti < nt; ++ti) {
    const int b = ti & 1;
    __syncthreads();  // implicit per-wave vmcnt(0) drain + barrier => tile ti landed everywhere
    if (ti + 1 < nt) stage_kv((ti + 1) * 64, b ^ 1);  // buf^1 dead since iter ti-1

    // hoist K fragments once (8 ds_reads; shared by all 4 mi QK blocks; dies before PV)
    bf16x8 kfr[2][4];
#pragma unroll
    for (int ks = 0; ks < 2; ++ks)
#pragma unroll
      for (int ni = 0; ni < 4; ++ni)
        kfr[ks][ni] = *(const bf16x8*)&Ks[b][(ni * 16 + lr) * 64 + ((ks * 4 + g) ^ (lr & 7)) * 8];

    // ---- interleaved: QK(p) on MFMA pipe, softmax(p-2) on VALU/TRANS pipe ----
    // lane holds S[q=mi*16+lr][k=16ni+4g+r]; P = exp2(S) (no max-subtract:
    // logits N(0,1)-scaled, max S' ~ 9 -> P <= ~2^9)
    f32x4 s[4][4];
    union pau { bf16x8 v; unsigned u[4]; };
    pau pa[4][2];  // [mi][ks], all indices compile-time after unroll
    __builtin_amdgcn_s_setprio(1);
#pragma unroll
    for (int p = 0; p < 6; ++p) {
      if (p < 4) {
        const int mi = p;
#pragma unroll
        for (int ni = 0; ni < 4; ++ni) s[mi][ni] = (f32x4){0.f, 0.f, 0.f, 0.f};
#pragma unroll
        for (int ks = 0; ks < 2; ++ks)
#pragma unroll
          for (int ni = 0; ni < 4; ++ni)
            s[mi][ni] = mfma16(kfr[ks][ni], qf[mi][ks], s[mi][ni]);
      }
      if (p >= 2) {
        const int mi = p - 2;
#pragma unroll
        for (int ni = 0; ni < 4; ++ni)
#pragma unroll
          for (int r = 0; r < 4; ++r)
            s[mi][ni][r] = __builtin_amdgcn_exp2f(s[mi][ni][r]);
#pragma unroll
        for (int ks = 0; ks < 2; ++ks) {
          pa[mi][ks].u[0] = cvtpk(s[mi][2 * ks][0], s[mi][2 * ks][1]);
          pa[mi][ks].u[1] = cvtpk(s[mi][2 * ks][2], s[mi][2 * ks][3]);
          pa[mi][ks].u[2] = cvtpk(s[mi][2 * ks + 1][0], s[mi][2 * ks + 1][1]);
          pa[mi][ks].u[3] = cvtpk(s[mi][2 * ks + 1][2], s[mi][2 * ks + 1][3]);
        }
      }
    }

    // ---- PV(ti): O += P V, l += P 1 ----
#pragma unroll
    for (int ks = 0; ks < 2; ++ks) {
#pragma unroll
      for (int ni = 0; ni < 4; ++ni) {
        bf16x8 vf = *(const bf16x8*)&Vs[b][(ni * 16 + lr) * 64 + ((ks * 4 + g) ^ (lr & 7)) * 8];
#pragma unroll
        for (int mi = 0; mi < 4; ++mi)
          o[mi][ni] = mfma16(pa[mi][ks].v, vf, o[mi][ni]);
      }
#pragma unroll
      for (int mi = 0; mi < 4; ++mi)
        acc_l[mi] = mfma16(pa[mi][ks].v, ones, acc_l[mi]);
    }
    __builtin_amdgcn_s_setprio(0);
  }

  // ---- epilogue: O /= l (no shuffles -- acc_l rows align with o rows) ----
  const int bb = bh >> 4, h = bh & (NHEAD - 1);
#pragma unroll
  for (int mi = 0; mi < 4; ++mi) {
    f32x4 inv;
#pragma unroll
    for (int r = 0; r < 4; ++r) inv[r] = 1.0f / acc_l[mi][r];
#pragma unroll
    for (int ni = 0; ni < 4; ++ni)
#pragma unroll
      for (int r = 0; r < 4; ++r) {
        int srow = q0 + w * 64 + mi * 16 + g * 4 + r;
        int col  = h * ND + ni * 16 + lr;
        AO[(size_t)(bb * NS + srow) * NHID + col] = f2bf(o[mi][ni][r] * inv[r]);
      }
  }
}

// ---------- output projection: AO [8192][1024] x Wo^T + bo -> fp32 out ----------
// 1-D grid of 256 with bijective XCD swizzle (256 = 8*32).

__global__ __launch_bounds__(512, 4) void gemm_out(
    const u16* __restrict__ AO, const u16* __restrict__ wob,
    const float* __restrict__ bo, float* __restrict__ out) {
  __shared__ __align__(16) u16 lds[3][12288];
  const int phys = blockIdx.x;
  const int lin = (phys & 7) * 32 + (phys >> 3);  // bijective XCD remap
  const int bm = (lin & 31) * 256;
  const int bn = (lin >> 5) * 128;

  f32x4 acc[4][4];
  gemm256_mainloop(AO, wob, bm, bn, lds, acc);

  const int t = threadIdx.x, w = t >> 6, l = t & 63, lr = l & 15, kh = l >> 4;
  const int wm = w >> 1, wn = w & 1;
#pragma unroll
  for (int mi = 0; mi < 4; ++mi)
#pragma unroll
    for (int ni = 0; ni < 4; ++ni)
#pragma unroll
      for (int r = 0; r < 4; ++r) {
        int m = bm + wm * 64 + mi * 16 + kh * 4 + r;
        int n = bn + wn * 64 + ni * 16 + lr;
        out[(size_t)m * NHID + n] = acc[mi][ni][r] + bo[n];
      }
}

// ---------- launch ----------

extern "C" void kernel_launch(void* const* d_in, const int* in_sizes, int n_in,
                              void* d_out, int out_size, void* d_ws, size_t ws_size,
                              hipStream_t stream) {
  const float* x  = (const float*)d_in[0];
  const float* Wq = (const float*)d_in[1];
  const float* bq = (const float*)d_in[2];
  const float* Wk = (const float*)d_in[3];
  const float* bk = (const float*)d_in[4];
  const float* Wv = (const float*)d_in[5];
  const float* bv = (const float*)d_in[6];
  const float* Wo = (const float*)d_in[7];
  const float* bo = (const float*)d_in[8];
  float* out = (float*)d_out;

  char* ws = (char*)d_ws;
  u16* xb  = (u16*)(ws + 0);         // 16 MB: x bf16 [8192][1024]
  u16* wqb = (u16*)(ws + 16777216);  // 2 MB each
  u16* wkb = (u16*)(ws + 18874368);
  u16* wvb = (u16*)(ws + 20971520);
  u16* wob = (u16*)(ws + 23068672);
  u16* Qb  = (u16*)(ws + 25165824);  // 16 MB [b,h,s,d] (pre-scaled by SC2F)
  u16* Kb  = (u16*)(ws + 41943040);  // 16 MB [b,h,s,d]
  u16* Vtb = (u16*)(ws + 58720256);  // 16 MB [b,h,d,s'] (k-permuted)
  u16* AOb = (u16*)(ws + 75497472);  // 16 MB [8192][1024]

  convert_f32_bf16<<<dim3(512, 5), 256, 0, stream>>>(x, Wq, Wk, Wv, Wo, xb, wqb, wkb, wvb, wob);
  gemm_qkv<<<768, 512, 0, stream>>>(xb, wqb, wkb, wvb, bq, bk, bv, Qb, Kb, Vtb);
  attn_kernel<<<dim3(8, 64), 256, 0, stream>>>(Qb, Kb, Vtb, AOb);
  gemm_out<<<256, 512, 0, stream>>>(AOb, wob, bo, out);
}

// Round 15
// 171.516 us; speedup vs baseline: 1.1842x; 1.1842x over previous
//
#include <hip/hip_runtime.h>
#include <hip/hip_bf16.h>
#include <stdint.h>
#include <math.h>

#define NB 4
#define NS 2048
#define NHID 1024
#define NHEAD 16
#define ND 64
#define NM (NB * NS)  // 8192 rows

typedef unsigned short u16;
typedef __attribute__((ext_vector_type(8))) short bf16x8;
typedef __attribute__((ext_vector_type(4))) float f32x4;

#define SC2F 0.18033688011112042f  // 0.125 * log2(e): Q pre-scale -> softmax in exp2 domain

// ---------- helpers ----------

__device__ __forceinline__ u16 f2bf(float f) {
  union { float f; unsigned u; } v; v.f = f;
  unsigned u = v.u;
  return (u16)((u + 0x7FFFu + ((u >> 16) & 1u)) >> 16);  // RNE, no NaN in data
}

// async global->LDS, 16B per lane. LDS dest is wave-uniform base; HW adds lane*16.
__device__ __forceinline__ void gload_lds16(const u16* g, u16* l) {
  __builtin_amdgcn_global_load_lds(
      (const __attribute__((address_space(1))) void*)g,
      (__attribute__((address_space(3))) void*)l, 16, 0, 0);
}

__device__ __forceinline__ f32x4 mfma16(bf16x8 a, bf16x8 b, f32x4 c) {
  return __builtin_amdgcn_mfma_f32_16x16x32_bf16(a, b, c, 0, 0, 0);
}

__device__ __forceinline__ unsigned cvtpk(float lo, float hi) {
  unsigned d;
  asm("v_cvt_pk_bf16_f32 %0, %1, %2" : "=v"(d) : "v"(lo), "v"(hi));
  return d;
}

// ---------- fp32 -> bf16 conversion (x + 4 weights in one launch) ----------

__global__ __launch_bounds__(256) void convert_f32_bf16(
    const float* __restrict__ x, const float* __restrict__ wq,
    const float* __restrict__ wk, const float* __restrict__ wv,
    const float* __restrict__ wo,
    u16* __restrict__ xb, u16* __restrict__ wqb, u16* __restrict__ wkb,
    u16* __restrict__ wvb, u16* __restrict__ wob) {
  const float* src; u16* dst; int n;
  switch (blockIdx.y) {
    case 0:  src = x;  dst = xb;  n = NM * NHID;   break;
    case 1:  src = wq; dst = wqb; n = NHID * NHID; break;
    case 2:  src = wk; dst = wkb; n = NHID * NHID; break;
    case 3:  src = wv; dst = wvb; n = NHID * NHID; break;
    default: src = wo; dst = wob; n = NHID * NHID; break;
  }
  int stride = gridDim.x * blockDim.x * 4;
  for (int i = (blockIdx.x * blockDim.x + threadIdx.x) * 4; i < n; i += stride) {
    float4 v = *reinterpret_cast<const float4*>(src + i);
    ushort4 o;
    o.x = f2bf(v.x); o.y = f2bf(v.y); o.z = f2bf(v.z); o.w = f2bf(v.w);
    *reinterpret_cast<ushort4*>(dst + i) = o;
  }
}

// ---------- 256x128 GEMM mainloop: C[m][n] = sum_k A[m][k] * Bw[n][k] ----------
// BK=32, 512 threads (8 waves as 4M x 2N, per-wave 64x64 out, acc[4][4]).
// Triple-buffered LDS (3 x 24KB = 72KB -> 2 blocks/CU), prefetch depth 2 with
// counted vmcnt(3) (never 0 in steady state). Linear LDS (BK=32 rows are
// bank-uniform for this ds_read_b128 pattern).
// NOTE (R14 lesson): natural 3-D grid dispatch order only. The 1-D XCD remap
// regressed qkv 60->103us (each XCD streamed all of x through its 4MB L2;
// natural order keeps concurrent blocks on correlated panels). 0-for-2 on
// block-remap experiments this session -- do not retry without in-round A/B.

#define GNKT 32  // K = 1024 / BK = 32

__device__ __forceinline__ void gemm256_mainloop(
    const u16* __restrict__ A, const u16* __restrict__ Bw,
    int bm, int bn, u16 (*lds)[12288], f32x4 (&acc)[4][4]) {
  const int t = threadIdx.x;          // 0..511
  const int w = t >> 6, l = t & 63;
  const int lr = l & 15, kh = l >> 4;
  const int wm = w >> 1, wn = w & 1;  // wave grid 4M x 2N

#pragma unroll
  for (int mi = 0; mi < 4; ++mi)
#pragma unroll
    for (int ni = 0; ni < 4; ++ni) acc[mi][ni] = (f32x4){0.f, 0.f, 0.f, 0.f};

  // stage K-tile kt into lds[buf]: A[256][32] = 2 loads/lane, B[128][32] = 1
  auto stage = [&](int kt, int buf) {
    const int k0 = kt * 32;
#pragma unroll
    for (int it = 0; it < 2; ++it) {
      int idx = it * 512 + t;                       // 0..1023 16B-chunks
      int row = idx >> 2, c = idx & 3;
      gload_lds16(A + (size_t)(bm + row) * NHID + k0 + c * 8,
                  lds[buf] + (size_t)(it * 512 + w * 64) * 8);
    }
    {
      int row = t >> 2, c = t & 3;                  // 512 chunks
      gload_lds16(Bw + (size_t)(bn + row) * NHID + k0 + c * 8,
                  lds[buf] + 8192 + (size_t)(w * 64) * 8);
    }
  };

  stage(0, 0);
  stage(1, 1);

  for (int kt = 0; kt < GNKT; ++kt) {
    const int buf = kt % 3;
    // force tile kt's 3 loads complete; leave tile kt+1's 3 in flight
    if (kt < GNKT - 1) asm volatile("s_waitcnt vmcnt(3)" ::: "memory");
    else               asm volatile("s_waitcnt vmcnt(0)" ::: "memory");
    __builtin_amdgcn_s_barrier();
    if (kt + 2 < GNKT) stage(kt + 2, (kt + 2) % 3);  // buf (kt-1)%3: free since last barrier

    const u16* Ab = lds[buf];
    const u16* Bb = lds[buf] + 8192;
    bf16x8 af[4], bfr[4];
#pragma unroll
    for (int mi = 0; mi < 4; ++mi)
      af[mi] = *(const bf16x8*)&Ab[(wm * 64 + mi * 16 + lr) * 32 + kh * 8];
#pragma unroll
    for (int ni = 0; ni < 4; ++ni)
      bfr[ni] = *(const bf16x8*)&Bb[(wn * 64 + ni * 16 + lr) * 32 + kh * 8];
    __builtin_amdgcn_s_setprio(1);
#pragma unroll
    for (int mi = 0; mi < 4; ++mi)
#pragma unroll
      for (int ni = 0; ni < 4; ++ni)
        acc[mi][ni] = mfma16(af[mi], bfr[ni], acc[mi][ni]);
    __builtin_amdgcn_s_setprio(0);
  }
}

// ---------- QKV projection (R12-proven 3-D grid, verbatim) ----------
// Q pre-scaled by SC2F (softmax runs in exp2 domain). V written transposed [b,h,d,s]
// AND k-permuted within each 32-block so attention's PV B-operand matches the
// lane-local P fragment order (k = 16u+4g+v stored at slot 8g+4u+v).

__global__ __launch_bounds__(512, 4) void gemm_qkv(
    const u16* __restrict__ xb,
    const u16* __restrict__ wqb, const u16* __restrict__ wkb, const u16* __restrict__ wvb,
    const float* __restrict__ bq, const float* __restrict__ bk, const float* __restrict__ bv,
    u16* __restrict__ Qo, u16* __restrict__ Ko, u16* __restrict__ Vo) {
  __shared__ __align__(16) u16 lds[3][12288];  // 72KB: 3 x (A 256x32 + B 128x32)
  const int which = blockIdx.z;
  const u16* Bw = (which == 0) ? wqb : (which == 1) ? wkb : wvb;
  const float* bias = (which == 0) ? bq : (which == 1) ? bk : bv;
  u16* outp = (which == 0) ? Qo : (which == 1) ? Ko : Vo;
  const int bm = blockIdx.x * 256, bn = blockIdx.y * 128;

  f32x4 acc[4][4];
  gemm256_mainloop(xb, Bw, bm, bn, lds, acc);

  const int t = threadIdx.x, w = t >> 6, l = t & 63, lr = l & 15, kh = l >> 4;
  const int wm = w >> 1, wn = w & 1;
#pragma unroll
  for (int mi = 0; mi < 4; ++mi)
#pragma unroll
    for (int ni = 0; ni < 4; ++ni)
#pragma unroll
      for (int r = 0; r < 4; ++r) {
        int m = bm + wm * 64 + mi * 16 + kh * 4 + r;
        int n = bn + wn * 64 + ni * 16 + lr;
        float v = acc[mi][ni][r] + bias[n];
        if (which == 0) v *= SC2F;
        int b = m >> 11, s = m & (NS - 1), h = n >> 6, d = n & (ND - 1);
        size_t addr;
        if (which < 2) {
          addr = (((size_t)(b * NHEAD + h)) * NS + s) * ND + d;  // [b,h,s,d]
        } else {
          // V^T [b,h,d,s'], s' = within-32-block permute: k=16u+4g2+v -> 8g2+4u+v
          int sp = (s & ~31) | (((s >> 2) & 3) * 8 + ((s >> 4) & 1) * 4 + (s & 3));
          addr = (((size_t)(b * NHEAD + h)) * ND + d) * NS + sp;
        }
        outp[addr] = f2bf(v);
      }
}

// ---------- flash attention (R14's mi-skew, kept) ----------
// R12-proven sync skeleton (2 buffers, one __syncthreads per tile, stage right
// after). Intra-tile mi-skew: unrolled p-loop issues QK(p) and softmax(p-2)
// interleaved, so exp2/cvt_pk VALU slots into matrix-pipe gaps while later QK
// MFMAs queue. K fragments hoisted to kfr (dies before PV; 256-VGPR budget at
// the grid-forced 2 blocks/CU). R13's cross-tile 3-buffer skew FAILED
// correctness -- do not reintroduce. R9: V frags NOT hoisted ahead of softmax.

__global__ __launch_bounds__(256, 2) void attn_kernel(
    const u16* __restrict__ Q, const u16* __restrict__ K,
    const u16* __restrict__ Vt, u16* __restrict__ AO) {
  __shared__ __align__(16) u16 Ks[2][64 * 64];    // 16KB double-buffered
  __shared__ __align__(16) u16 Vs[2][64 * 64];    // 16KB double-buffered

  const int t = threadIdx.x, w = t >> 6, l = t & 63;
  const int lr = l & 15, g = l >> 4;
  const int bh = blockIdx.y;
  const int q0 = blockIdx.x * 256;

  const u16* Qh = Q  + (size_t)bh * NS * ND;
  const u16* Kh = K  + (size_t)bh * NS * ND;
  const u16* Vh = Vt + (size_t)bh * NS * ND;  // [d][s'] (k-permuted)

  // Q fragments straight from global into registers (no LDS round-trip)
  bf16x8 qf[4][2];
#pragma unroll
  for (int mi = 0; mi < 4; ++mi)
#pragma unroll
    for (int ks = 0; ks < 2; ++ks)
      qf[mi][ks] = *(const bf16x8*)(Qh + (size_t)(q0 + w * 64 + mi * 16 + lr) * ND + ks * 32 + g * 8);

  // all-ones bf16 B-operand (layout-proof: every element equal)
  bf16x8 ones;
#pragma unroll
  for (int i = 0; i < 8; ++i) ones[i] = (short)0x3F80;

  // stage tile kt into buffer b: 4 loads/lane, pre-swizzled source
  auto stage_kv = [&](int kt, int b) {
#pragma unroll
    for (int j = 0; j < 2; ++j) {
      int idx = j * 256 + t;
      int row = idx >> 3, sch = (idx & 7) ^ (row & 7);
      gload_lds16(Kh + (size_t)(kt + row) * ND + sch * 8, Ks[b] + (size_t)(j * 256 + w * 64) * 8);
      gload_lds16(Vh + (size_t)row * NS + kt + sch * 8,   Vs[b] + (size_t)(j * 256 + w * 64) * 8);
    }
  };

  stage_kv(0, 0);

  f32x4 o[4][4];
  f32x4 acc_l[4];  // row-sum accumulators; acc_l[mi][r] = l for row q=4g+r (matches o)
#pragma unroll
  for (int mi = 0; mi < 4; ++mi) {
#pragma unroll
    for (int ni = 0; ni < 4; ++ni) o[mi][ni] = (f32x4){0.f, 0.f, 0.f, 0.f};
    acc_l[mi] = (f32x4){0.f, 0.f, 0.f, 0.f};
  }

  const int nt = NS / 64;
  for (int ti = 0; ti < nt; ++ti) {
    const int b = ti & 1;
    __syncthreads();  // implicit per-wave vmcnt(0) drain + barrier => tile ti landed everywhere
    if (ti + 1 < nt) stage_kv((ti + 1) * 64, b ^ 1);  // buf^1 dead since iter ti-1

    // hoist K fragments once (8 ds_reads; shared by all 4 mi QK blocks; dies before PV)
    bf16x8 kfr[2][4];
#pragma unroll
    for (int ks = 0; ks < 2; ++ks)
#pragma unroll
      for (int ni = 0; ni < 4; ++ni)
        kfr[ks][ni] = *(const bf16x8*)&Ks[b][(ni * 16 + lr) * 64 + ((ks * 4 + g) ^ (lr & 7)) * 8];

    // ---- interleaved: QK(p) on MFMA pipe, softmax(p-2) on VALU/TRANS pipe ----
    // lane holds S[q=mi*16+lr][k=16ni+4g+r]; P = exp2(S) (no max-subtract:
    // logits N(0,1)-scaled, max S' ~ 9 -> P <= ~2^9)
    f32x4 s[4][4];
    union pau { bf16x8 v; unsigned u[4]; };
    pau pa[4][2];  // [mi][ks], all indices compile-time after unroll
    __builtin_amdgcn_s_setprio(1);
#pragma unroll
    for (int p = 0; p < 6; ++p) {
      if (p < 4) {
        const int mi = p;
#pragma unroll
        for (int ni = 0; ni < 4; ++ni) s[mi][ni] = (f32x4){0.f, 0.f, 0.f, 0.f};
#pragma unroll
        for (int ks = 0; ks < 2; ++ks)
#pragma unroll
          for (int ni = 0; ni < 4; ++ni)
            s[mi][ni] = mfma16(kfr[ks][ni], qf[mi][ks], s[mi][ni]);
      }
      if (p >= 2) {
        const int mi = p - 2;
#pragma unroll
        for (int ni = 0; ni < 4; ++ni)
#pragma unroll
          for (int r = 0; r < 4; ++r)
            s[mi][ni][r] = __builtin_amdgcn_exp2f(s[mi][ni][r]);
#pragma unroll
        for (int ks = 0; ks < 2; ++ks) {
          pa[mi][ks].u[0] = cvtpk(s[mi][2 * ks][0], s[mi][2 * ks][1]);
          pa[mi][ks].u[1] = cvtpk(s[mi][2 * ks][2], s[mi][2 * ks][3]);
          pa[mi][ks].u[2] = cvtpk(s[mi][2 * ks + 1][0], s[mi][2 * ks + 1][1]);
          pa[mi][ks].u[3] = cvtpk(s[mi][2 * ks + 1][2], s[mi][2 * ks + 1][3]);
        }
      }
    }

    // ---- PV(ti): O += P V, l += P 1 ----
#pragma unroll
    for (int ks = 0; ks < 2; ++ks) {
#pragma unroll
      for (int ni = 0; ni < 4; ++ni) {
        bf16x8 vf = *(const bf16x8*)&Vs[b][(ni * 16 + lr) * 64 + ((ks * 4 + g) ^ (lr & 7)) * 8];
#pragma unroll
        for (int mi = 0; mi < 4; ++mi)
          o[mi][ni] = mfma16(pa[mi][ks].v, vf, o[mi][ni]);
      }
#pragma unroll
      for (int mi = 0; mi < 4; ++mi)
        acc_l[mi] = mfma16(pa[mi][ks].v, ones, acc_l[mi]);
    }
    __builtin_amdgcn_s_setprio(0);
  }

  // ---- epilogue: O /= l (no shuffles -- acc_l rows align with o rows) ----
  const int bb = bh >> 4, h = bh & (NHEAD - 1);
#pragma unroll
  for (int mi = 0; mi < 4; ++mi) {
    f32x4 inv;
#pragma unroll
    for (int r = 0; r < 4; ++r) inv[r] = 1.0f / acc_l[mi][r];
#pragma unroll
    for (int ni = 0; ni < 4; ++ni)
#pragma unroll
      for (int r = 0; r < 4; ++r) {
        int srow = q0 + w * 64 + mi * 16 + g * 4 + r;
        int col  = h * ND + ni * 16 + lr;
        AO[(size_t)(bb * NS + srow) * NHID + col] = f2bf(o[mi][ni][r] * inv[r]);
      }
  }
}

// ---------- output projection (R12-proven 2-D grid, verbatim) ----------

__global__ __launch_bounds__(512, 4) void gemm_out(
    const u16* __restrict__ AO, const u16* __restrict__ wob,
    const float* __restrict__ bo, float* __restrict__ out) {
  __shared__ __align__(16) u16 lds[3][12288];
  const int bm = blockIdx.x * 256, bn = blockIdx.y * 128;

  f32x4 acc[4][4];
  gemm256_mainloop(AO, wob, bm, bn, lds, acc);

  const int t = threadIdx.x, w = t >> 6, l = t & 63, lr = l & 15, kh = l >> 4;
  const int wm = w >> 1, wn = w & 1;
#pragma unroll
  for (int mi = 0; mi < 4; ++mi)
#pragma unroll
    for (int ni = 0; ni < 4; ++ni)
#pragma unroll
      for (int r = 0; r < 4; ++r) {
        int m = bm + wm * 64 + mi * 16 + kh * 4 + r;
        int n = bn + wn * 64 + ni * 16 + lr;
        out[(size_t)m * NHID + n] = acc[mi][ni][r] + bo[n];
      }
}

// ---------- launch ----------

extern "C" void kernel_launch(void* const* d_in, const int* in_sizes, int n_in,
                              void* d_out, int out_size, void* d_ws, size_t ws_size,
                              hipStream_t stream) {
  const float* x  = (const float*)d_in[0];
  const float* Wq = (const float*)d_in[1];
  const float* bq = (const float*)d_in[2];
  const float* Wk = (const float*)d_in[3];
  const float* bk = (const float*)d_in[4];
  const float* Wv = (const float*)d_in[5];
  const float* bv = (const float*)d_in[6];
  const float* Wo = (const float*)d_in[7];
  const float* bo = (const float*)d_in[8];
  float* out = (float*)d_out;

  char* ws = (char*)d_ws;
  u16* xb  = (u16*)(ws + 0);         // 16 MB: x bf16 [8192][1024]
  u16* wqb = (u16*)(ws + 16777216);  // 2 MB each
  u16* wkb = (u16*)(ws + 18874368);
  u16* wvb = (u16*)(ws + 20971520);
  u16* wob = (u16*)(ws + 23068672);
  u16* Qb  = (u16*)(ws + 25165824);  // 16 MB [b,h,s,d] (pre-scaled by SC2F)
  u16* Kb  = (u16*)(ws + 41943040);  // 16 MB [b,h,s,d]
  u16* Vtb = (u16*)(ws + 58720256);  // 16 MB [b,h,d,s'] (k-permuted)
  u16* AOb = (u16*)(ws + 75497472);  // 16 MB [8192][1024]

  convert_f32_bf16<<<dim3(512, 5), 256, 0, stream>>>(x, Wq, Wk, Wv, Wo, xb, wqb, wkb, wvb, wob);
  gemm_qkv<<<dim3(32, 8, 3), 512, 0, stream>>>(xb, wqb, wkb, wvb, bq, bk, bv, Qb, Kb, Vtb);
  attn_kernel<<<dim3(8, 64), 256, 0, stream>>>(Qb, Kb, Vtb, AOb);
  gemm_out<<<dim3(32, 8), 512, 0, stream>>>(AOb, wob, bo, out);
}